// Round 6
// baseline (3400.964 us; speedup 1.0000x reference)
//
#include <hip/hip_runtime.h>
#include <hip/hip_fp16.h>

#define TPB 256
static constexpr unsigned HASH_MASK = (1u << 19) - 1u;
// log(log(1/0.99)) - log(4.0) - 0.5
static constexpr float OFFSETC = -6.4864436218f;
static constexpr int NPTS = 4096 * 128;         // 524288 sample points
static constexpr int NLVL = 16;
static constexpr int HASHSZ = 1 << 19;

// ws layout: [0, 32MiB) fp16 table (level-major, __half2 per entry)
//            [32MiB, 64MiB) fp16 enc features enc16[l*NPTS + p] (__half2)
static constexpr size_t TAB16_BYTES = (size_t)NLVL * HASHSZ * sizeof(__half2); // 32 MiB
static constexpr size_t ENC16_BYTES = (size_t)NLVL * NPTS * sizeof(__half2);   // 32 MiB

__device__ __constant__ float d_RES[16] = {16.f, 23.f, 33.f, 48.f, 70.f, 101.f, 147.f, 212.f,
                                           307.f, 445.f, 645.f, 933.f, 1351.f, 1955.f, 2830.f, 4096.f};

// ---------------- kernel 1: f32 table -> fp16 table ----------------
__global__ __launch_bounds__(TPB) void convert_table_kernel(
    const float2* __restrict__ src, __half2* __restrict__ dst)
{
    const int i = blockIdx.x * TPB + threadIdx.x;   // one entry per thread
    const float2 v = src[i];
    dst[i] = __floats2half2_rn(v.x, v.y);
}

// ---------------- kernel 2: level-major hash encode ----------------
// bid = x + 8*(c + 2048*h); level = x + 8*h; chunk c covers points [c*256, c*256+256)
// bid % 8 == level % 8  ->  XCD x serves only levels {x, x+8} (4 MB fp16 = its L2)
__global__ __launch_bounds__(TPB, 8) void encode_kernel(
    const float* __restrict__ xyz,
    const __half2* __restrict__ tab16,
    __half2* __restrict__ enc16)
{
    const unsigned bid = blockIdx.x;
    const unsigned x = bid & 7u;
    const unsigned q = bid >> 3;
    const unsigned c = q & 2047u;
    const unsigned h = q >> 11;
    const int l = (int)(x + 8u * h);
    const int p = (int)(c * TPB + threadIdx.x);

    const float px0 = xyz[3 * p + 0];
    const float py0 = xyz[3 * p + 1];
    const float pz0 = xyz[3 * p + 2];

    const float res = d_RES[l];
    const float px = px0 * res, py = py0 * res, pz = pz0 * res;
    const float fx0 = floorf(px), fy0 = floorf(py), fz0 = floorf(pz);
    const float fx = px - fx0, fy = py - fy0, fz = pz - fz0;
    const unsigned ix = (unsigned)fx0, iy = (unsigned)fy0, iz = (unsigned)fz0;
    const unsigned hx0 = ix,               hx1 = ix + 1u;
    const unsigned hy0 = iy * 2654435761u, hy1 = hy0 + 2654435761u;
    const unsigned hz0 = iz * 805459861u,  hz1 = hz0 + 805459861u;
    const __half2* tab = tab16 + ((size_t)l << 19);
    const __half2 q000 = tab[(hx0 ^ hy0 ^ hz0) & HASH_MASK];
    const __half2 q001 = tab[(hx0 ^ hy0 ^ hz1) & HASH_MASK];
    const __half2 q010 = tab[(hx0 ^ hy1 ^ hz0) & HASH_MASK];
    const __half2 q011 = tab[(hx0 ^ hy1 ^ hz1) & HASH_MASK];
    const __half2 q100 = tab[(hx1 ^ hy0 ^ hz0) & HASH_MASK];
    const __half2 q101 = tab[(hx1 ^ hy0 ^ hz1) & HASH_MASK];
    const __half2 q110 = tab[(hx1 ^ hy1 ^ hz0) & HASH_MASK];
    const __half2 q111 = tab[(hx1 ^ hy1 ^ hz1) & HASH_MASK];
    const float2 t000 = __half22float2(q000), t001 = __half22float2(q001);
    const float2 t010 = __half22float2(q010), t011 = __half22float2(q011);
    const float2 t100 = __half22float2(q100), t101 = __half22float2(q101);
    const float2 t110 = __half22float2(q110), t111 = __half22float2(q111);
    const float gx = 1.f - fx, gy = 1.f - fy, gz = 1.f - fz;
    const float w000 = gx * gy * gz, w001 = gx * gy * fz;
    const float w010 = gx * fy * gz, w011 = gx * fy * fz;
    const float w100 = fx * gy * gz, w101 = fx * gy * fz;
    const float w110 = fx * fy * gz, w111 = fx * fy * fz;
    float a0 = w000 * t000.x; float a1 = w000 * t000.y;
    a0 += w001 * t001.x; a1 += w001 * t001.y;
    a0 += w010 * t010.x; a1 += w010 * t010.y;
    a0 += w011 * t011.x; a1 += w011 * t011.y;
    a0 += w100 * t100.x; a1 += w100 * t100.y;
    a0 += w101 * t101.x; a1 += w101 * t101.y;
    a0 += w110 * t110.x; a1 += w110 * t110.y;
    a0 += w111 * t111.x; a1 += w111 * t111.y;

    enc16[(size_t)l * NPTS + p] = __floats2half2_rn(a0, a1);
}

// ---------------- kernel 3: MLPs + volrend scan ----------------
__global__ __launch_bounds__(TPB, 3) void mlp_kernel(
    const __half2* __restrict__ enc16,
    const float* __restrict__ delta,
    const float* __restrict__ w_in,
    const float* __restrict__ w_out,
    const float* __restrict__ rgb_w1,
    const float* __restrict__ rgb_w2,
    const float* __restrict__ rgb_w3,
    float* __restrict__ out)
{
    __shared__ float s_w_inT[64 * 32];   // [j][i]  (w_in is (32,64))
    __shared__ float s_w_out[64 * 16];   // [j][k]
    __shared__ float s_rgb_w1T[64 * 16]; // [j][i], padded 15->16 with 0
    __shared__ float s_rgb_w2T[64 * 64]; // [k][j]
    __shared__ float s_rgb_w3[64 * 3];   // [j][c]
    __shared__ float s_wavetot[4];

    const int tid = threadIdx.x;
    for (int i = tid; i < 32 * 64; i += TPB) { int r = i >> 6, cc = i & 63; s_w_inT[cc * 32 + r] = w_in[i]; }
    for (int i = tid; i < 64 * 16; i += TPB) s_w_out[i] = w_out[i];
    for (int i = tid; i < 64 * 16; i += TPB) { int j = i >> 4, k = i & 15; s_rgb_w1T[i] = (k < 15) ? rgb_w1[k * 64 + j] : 0.f; }
    for (int i = tid; i < 64 * 64; i += TPB) { int j = i >> 6, k = i & 63; s_rgb_w2T[k * 64 + j] = rgb_w2[i]; }
    for (int i = tid; i < 64 * 3; i += TPB) s_rgb_w3[i] = rgb_w3[i];
    __syncthreads();

    const int p = blockIdx.x * TPB + tid;

    float enc[32];
    #pragma unroll
    for (int l = 0; l < 16; ++l) {
        const float2 e = __half22float2(enc16[(size_t)l * NPTS + p]);
        enc[2 * l + 0] = e.x;
        enc[2 * l + 1] = e.y;
    }

    // layer1 (32->64, relu) fused with layer2 (64->16)
    float raw[16];
    #pragma unroll
    for (int k = 0; k < 16; ++k) raw[k] = 0.f;
    #pragma unroll
    for (int j = 0; j < 64; ++j) {
        const float4* wr = (const float4*)&s_w_inT[j * 32];
        float acc = 0.f;
        #pragma unroll
        for (int i = 0; i < 8; ++i) {
            const float4 w4 = wr[i];
            acc += w4.x * enc[4 * i + 0] + w4.y * enc[4 * i + 1]
                 + w4.z * enc[4 * i + 2] + w4.w * enc[4 * i + 3];
        }
        const float hj = fmaxf(acc, 0.f);
        const float4* wo = (const float4*)&s_w_out[j * 16];
        #pragma unroll
        for (int k = 0; k < 4; ++k) {
            const float4 w4 = wo[k];
            raw[4 * k + 0] += hj * w4.x;
            raw[4 * k + 1] += hj * w4.y;
            raw[4 * k + 2] += hj * w4.z;
            raw[4 * k + 3] += hj * w4.w;
        }
    }

    // volrend weights: per-ray scan over S=128 (2 waves per ray)
    const float dlt = delta[p];
    const float dd = expf(raw[0] + OFFSETC) * dlt;
    float v = dd;
    const int lane = tid & 63;
    #pragma unroll
    for (int d = 1; d < 64; d <<= 1) {
        const float n = __shfl_up(v, d, 64);
        if (lane >= d) v += n;
    }
    const int wv = tid >> 6;
    if (lane == 63) s_wavetot[wv] = v;
    __syncthreads();
    const float prev = (wv & 1) ? s_wavetot[wv - 1] : 0.f;
    const float excl = v - dd + prev;
    const float wgt = (1.f - expf(-dd)) * expf(-excl);

    // rgb MLP
    float f2[16];
    #pragma unroll
    for (int i = 0; i < 15; ++i) f2[i] = raw[i + 1];
    f2[15] = 0.f;

    float h1[64];
    #pragma unroll
    for (int j = 0; j < 64; ++j) {
        const float4* w1 = (const float4*)&s_rgb_w1T[j * 16];
        float acc = 0.f;
        #pragma unroll
        for (int i = 0; i < 4; ++i) {
            const float4 w4 = w1[i];
            acc += w4.x * f2[4 * i + 0] + w4.y * f2[4 * i + 1]
                 + w4.z * f2[4 * i + 2] + w4.w * f2[4 * i + 3];
        }
        h1[j] = fmaxf(acc, 0.f);
    }

    float r0 = 0.f, r1 = 0.f, r2 = 0.f;
    #pragma unroll
    for (int k = 0; k < 64; ++k) {
        const float4* w2 = (const float4*)&s_rgb_w2T[k * 64];
        float acc = 0.f;
        #pragma unroll
        for (int qq = 0; qq < 16; ++qq) {
            const float4 w4 = w2[qq];
            acc += w4.x * h1[4 * qq + 0] + w4.y * h1[4 * qq + 1]
                 + w4.z * h1[4 * qq + 2] + w4.w * h1[4 * qq + 3];
        }
        const float h2k = fmaxf(acc, 0.f);
        r0 += h2k * s_rgb_w3[k * 3 + 0];
        r1 += h2k * s_rgb_w3[k * 3 + 1];
        r2 += h2k * s_rgb_w3[k * 3 + 2];
    }
    const float s0 = 1.f / (1.f + expf(-r0));
    const float s1 = 1.f / (1.f + expf(-r1));
    const float s2 = 1.f / (1.f + expf(-r2));

    float4 o;
    o.x = wgt; o.y = s0; o.z = s1; o.w = s2;
    ((float4*)out)[p] = o;
}

// ---------------- fallback: round-4 fused kernel (used only if ws too small) ----------------
__global__ __launch_bounds__(TPB, 2) void density_field_fused(
    const float* __restrict__ xyz, const float* __restrict__ delta,
    const float* __restrict__ table, const float* __restrict__ w_in,
    const float* __restrict__ w_out, const float* __restrict__ rgb_w1,
    const float* __restrict__ rgb_w2, const float* __restrict__ rgb_w3,
    float* __restrict__ out)
{
    __shared__ float s_w_inT[64 * 32];
    __shared__ float s_w_out[64 * 16];
    __shared__ float s_rgb_w1T[64 * 16];
    __shared__ float s_rgb_w2T[64 * 64];
    __shared__ float s_rgb_w3[64 * 3];
    __shared__ float s_wavetot[4];

    const int tid = threadIdx.x;
    for (int i = tid; i < 32 * 64; i += TPB) { int r = i >> 6, cc = i & 63; s_w_inT[cc * 32 + r] = w_in[i]; }
    for (int i = tid; i < 64 * 16; i += TPB) s_w_out[i] = w_out[i];
    for (int i = tid; i < 64 * 16; i += TPB) { int j = i >> 4, k = i & 15; s_rgb_w1T[i] = (k < 15) ? rgb_w1[k * 64 + j] : 0.f; }
    for (int i = tid; i < 64 * 64; i += TPB) { int j = i >> 6, k = i & 63; s_rgb_w2T[k * 64 + j] = rgb_w2[i]; }
    for (int i = tid; i < 64 * 3; i += TPB) s_rgb_w3[i] = rgb_w3[i];
    __syncthreads();

    const int p = blockIdx.x * TPB + tid;
    const float x = xyz[3 * p + 0], y = xyz[3 * p + 1], z = xyz[3 * p + 2];

    float enc[32];
    #pragma unroll
    for (int l = 0; l < 16; ++l) {
        const float res = d_RES[l];
        const float px = x * res, py = y * res, pz = z * res;
        const float fx0 = floorf(px), fy0 = floorf(py), fz0 = floorf(pz);
        const float fx = px - fx0, fy = py - fy0, fz = pz - fz0;
        const unsigned ix = (unsigned)fx0, iy = (unsigned)fy0, iz = (unsigned)fz0;
        const unsigned hx0 = ix, hx1 = ix + 1u;
        const unsigned hy0 = iy * 2654435761u, hy1 = hy0 + 2654435761u;
        const unsigned hz0 = iz * 805459861u,  hz1 = hz0 + 805459861u;
        const float2* tab = (const float2*)table + ((size_t)l << 19);
        const float2 t000 = tab[(hx0 ^ hy0 ^ hz0) & HASH_MASK];
        const float2 t001 = tab[(hx0 ^ hy0 ^ hz1) & HASH_MASK];
        const float2 t010 = tab[(hx0 ^ hy1 ^ hz0) & HASH_MASK];
        const float2 t011 = tab[(hx0 ^ hy1 ^ hz1) & HASH_MASK];
        const float2 t100 = tab[(hx1 ^ hy0 ^ hz0) & HASH_MASK];
        const float2 t101 = tab[(hx1 ^ hy0 ^ hz1) & HASH_MASK];
        const float2 t110 = tab[(hx1 ^ hy1 ^ hz0) & HASH_MASK];
        const float2 t111 = tab[(hx1 ^ hy1 ^ hz1) & HASH_MASK];
        const float gx = 1.f - fx, gy = 1.f - fy, gz = 1.f - fz;
        const float w000 = gx * gy * gz, w001 = gx * gy * fz;
        const float w010 = gx * fy * gz, w011 = gx * fy * fz;
        const float w100 = fx * gy * gz, w101 = fx * gy * fz;
        const float w110 = fx * fy * gz, w111 = fx * fy * fz;
        float a0 = w000 * t000.x; float a1 = w000 * t000.y;
        a0 += w001 * t001.x; a1 += w001 * t001.y;
        a0 += w010 * t010.x; a1 += w010 * t010.y;
        a0 += w011 * t011.x; a1 += w011 * t011.y;
        a0 += w100 * t100.x; a1 += w100 * t100.y;
        a0 += w101 * t101.x; a1 += w101 * t101.y;
        a0 += w110 * t110.x; a1 += w110 * t110.y;
        a0 += w111 * t111.x; a1 += w111 * t111.y;
        enc[2 * l + 0] = a0; enc[2 * l + 1] = a1;
    }

    float raw[16];
    #pragma unroll
    for (int k = 0; k < 16; ++k) raw[k] = 0.f;
    #pragma unroll
    for (int j = 0; j < 64; ++j) {
        const float4* wr = (const float4*)&s_w_inT[j * 32];
        float acc = 0.f;
        #pragma unroll
        for (int i = 0; i < 8; ++i) {
            const float4 w4 = wr[i];
            acc += w4.x * enc[4 * i + 0] + w4.y * enc[4 * i + 1]
                 + w4.z * enc[4 * i + 2] + w4.w * enc[4 * i + 3];
        }
        const float hj = fmaxf(acc, 0.f);
        const float4* wo = (const float4*)&s_w_out[j * 16];
        #pragma unroll
        for (int k = 0; k < 4; ++k) {
            const float4 w4 = wo[k];
            raw[4 * k + 0] += hj * w4.x; raw[4 * k + 1] += hj * w4.y;
            raw[4 * k + 2] += hj * w4.z; raw[4 * k + 3] += hj * w4.w;
        }
    }

    const float dlt = delta[p];
    const float dd = expf(raw[0] + OFFSETC) * dlt;
    float v = dd;
    const int lane = tid & 63;
    #pragma unroll
    for (int d = 1; d < 64; d <<= 1) {
        const float n = __shfl_up(v, d, 64);
        if (lane >= d) v += n;
    }
    const int wv = tid >> 6;
    if (lane == 63) s_wavetot[wv] = v;
    __syncthreads();
    const float prev = (wv & 1) ? s_wavetot[wv - 1] : 0.f;
    const float excl = v - dd + prev;
    const float wgt = (1.f - expf(-dd)) * expf(-excl);

    float f2[16];
    #pragma unroll
    for (int i = 0; i < 15; ++i) f2[i] = raw[i + 1];
    f2[15] = 0.f;

    float h1[64];
    #pragma unroll
    for (int j = 0; j < 64; ++j) {
        const float4* w1 = (const float4*)&s_rgb_w1T[j * 16];
        float acc = 0.f;
        #pragma unroll
        for (int i = 0; i < 4; ++i) {
            const float4 w4 = w1[i];
            acc += w4.x * f2[4 * i + 0] + w4.y * f2[4 * i + 1]
                 + w4.z * f2[4 * i + 2] + w4.w * f2[4 * i + 3];
        }
        h1[j] = fmaxf(acc, 0.f);
    }
    float r0 = 0.f, r1 = 0.f, r2 = 0.f;
    #pragma unroll
    for (int k = 0; k < 64; ++k) {
        const float4* w2 = (const float4*)&s_rgb_w2T[k * 64];
        float acc = 0.f;
        #pragma unroll
        for (int qq = 0; qq < 16; ++qq) {
            const float4 w4 = w2[qq];
            acc += w4.x * h1[4 * qq + 0] + w4.y * h1[4 * qq + 1]
                 + w4.z * h1[4 * qq + 2] + w4.w * h1[4 * qq + 3];
        }
        const float h2k = fmaxf(acc, 0.f);
        r0 += h2k * s_rgb_w3[k * 3 + 0];
        r1 += h2k * s_rgb_w3[k * 3 + 1];
        r2 += h2k * s_rgb_w3[k * 3 + 2];
    }
    const float s0 = 1.f / (1.f + expf(-r0));
    const float s1 = 1.f / (1.f + expf(-r1));
    const float s2 = 1.f / (1.f + expf(-r2));
    float4 o; o.x = wgt; o.y = s0; o.z = s1; o.w = s2;
    ((float4*)out)[p] = o;
}

extern "C" void kernel_launch(void* const* d_in, const int* in_sizes, int n_in,
                              void* d_out, int out_size, void* d_ws, size_t ws_size,
                              hipStream_t stream) {
    const float* xyz    = (const float*)d_in[0];
    const float* delta  = (const float*)d_in[1];
    const float* table  = (const float*)d_in[2];
    const float* w_in   = (const float*)d_in[3];
    const float* w_out  = (const float*)d_in[4];
    const float* rgb_w1 = (const float*)d_in[5];
    const float* rgb_w2 = (const float*)d_in[6];
    const float* rgb_w3 = (const float*)d_in[7];
    float* outp = (float*)d_out;

    if (ws_size >= TAB16_BYTES + ENC16_BYTES) {
        __half2* tab16 = (__half2*)d_ws;
        __half2* enc16 = (__half2*)((char*)d_ws + TAB16_BYTES);

        // 1) table f32 -> fp16   (one thread per entry: 16*2^19 = 8.4M entries)
        convert_table_kernel<<<(NLVL * HASHSZ) / TPB, TPB, 0, stream>>>(
            (const float2*)table, tab16);

        // 2) level-major encode: 16 levels * 2048 chunks = 32768 blocks
        encode_kernel<<<NLVL * (NPTS / TPB), TPB, 0, stream>>>(xyz, tab16, enc16);

        // 3) MLPs + scan
        mlp_kernel<<<NPTS / TPB, TPB, 0, stream>>>(
            enc16, delta, w_in, w_out, rgb_w1, rgb_w2, rgb_w3, outp);
    } else {
        density_field_fused<<<NPTS / TPB, TPB, 0, stream>>>(
            xyz, delta, table, w_in, w_out, rgb_w1, rgb_w2, rgb_w3, outp);
    }
}

// Round 13
// 2125.396 us; speedup vs baseline: 1.6002x; 1.6002x over previous
//
#include <hip/hip_runtime.h>
#include <hip/hip_fp16.h>

#define TPB 256
static constexpr unsigned HASH_MASK = (1u << 19) - 1u;
// log(log(1/0.99)) - log(4.0) - 0.5
static constexpr float OFFSETC = -6.4864436218f;
static constexpr int NPTS = 4096 * 128;         // 524288 sample points
static constexpr int NLVL = 16;
static constexpr int HASHSZ = 1 << 19;

// ws layout: [0, 32MiB) fp16 table (level-major, __half2 per entry)
//            [32MiB, 64MiB) fp16 enc features enc16[l*NPTS + p] (__half2)
static constexpr size_t TAB16_BYTES = (size_t)NLVL * HASHSZ * sizeof(__half2); // 32 MiB
static constexpr size_t ENC16_BYTES = (size_t)NLVL * NPTS * sizeof(__half2);   // 32 MiB

__device__ __constant__ float d_RES[16] = {16.f, 23.f, 33.f, 48.f, 70.f, 101.f, 147.f, 212.f,
                                           307.f, 445.f, 645.f, 933.f, 1351.f, 1955.f, 2830.f, 4096.f};

// ---------------- kernel 1: f32 table -> fp16 table ----------------
__global__ __launch_bounds__(TPB) void convert_table_kernel(
    const float2* __restrict__ src, __half2* __restrict__ dst)
{
    const int i = blockIdx.x * TPB + threadIdx.x;   // one entry per thread
    const float2 v = src[i];
    dst[i] = __floats2half2_rn(v.x, v.y);
}

// ---------------- kernel 2: level-major hash encode ----------------
// bid = x + 8*(c + 2048*h); level = x + 8*h; chunk c covers points [c*256, c*256+256)
// bid % 8 == level % 8  ->  XCD x serves only levels {x, x+8} (4 MB fp16 = its L2)
__global__ __launch_bounds__(TPB, 8) void encode_kernel(
    const float* __restrict__ xyz,
    const __half2* __restrict__ tab16,
    __half2* __restrict__ enc16)
{
    const unsigned bid = blockIdx.x;
    const unsigned x = bid & 7u;
    const unsigned q = bid >> 3;
    const unsigned c = q & 2047u;
    const unsigned h = q >> 11;
    const int l = (int)(x + 8u * h);
    const int p = (int)(c * TPB + threadIdx.x);

    const float px0 = xyz[3 * p + 0];
    const float py0 = xyz[3 * p + 1];
    const float pz0 = xyz[3 * p + 2];

    const float res = d_RES[l];
    const float px = px0 * res, py = py0 * res, pz = pz0 * res;
    const float fx0 = floorf(px), fy0 = floorf(py), fz0 = floorf(pz);
    const float fx = px - fx0, fy = py - fy0, fz = pz - fz0;
    const unsigned ix = (unsigned)fx0, iy = (unsigned)fy0, iz = (unsigned)fz0;
    const unsigned hx0 = ix,               hx1 = ix + 1u;
    const unsigned hy0 = iy * 2654435761u, hy1 = hy0 + 2654435761u;
    const unsigned hz0 = iz * 805459861u,  hz1 = hz0 + 805459861u;
    const __half2* tab = tab16 + ((size_t)l << 19);
    const __half2 q000 = tab[(hx0 ^ hy0 ^ hz0) & HASH_MASK];
    const __half2 q001 = tab[(hx0 ^ hy0 ^ hz1) & HASH_MASK];
    const __half2 q010 = tab[(hx0 ^ hy1 ^ hz0) & HASH_MASK];
    const __half2 q011 = tab[(hx0 ^ hy1 ^ hz1) & HASH_MASK];
    const __half2 q100 = tab[(hx1 ^ hy0 ^ hz0) & HASH_MASK];
    const __half2 q101 = tab[(hx1 ^ hy0 ^ hz1) & HASH_MASK];
    const __half2 q110 = tab[(hx1 ^ hy1 ^ hz0) & HASH_MASK];
    const __half2 q111 = tab[(hx1 ^ hy1 ^ hz1) & HASH_MASK];
    const float2 t000 = __half22float2(q000), t001 = __half22float2(q001);
    const float2 t010 = __half22float2(q010), t011 = __half22float2(q011);
    const float2 t100 = __half22float2(q100), t101 = __half22float2(q101);
    const float2 t110 = __half22float2(q110), t111 = __half22float2(q111);
    const float gx = 1.f - fx, gy = 1.f - fy, gz = 1.f - fz;
    const float w000 = gx * gy * gz, w001 = gx * gy * fz;
    const float w010 = gx * fy * gz, w011 = gx * fy * fz;
    const float w100 = fx * gy * gz, w101 = fx * gy * fz;
    const float w110 = fx * fy * gz, w111 = fx * fy * fz;
    float a0 = w000 * t000.x; float a1 = w000 * t000.y;
    a0 += w001 * t001.x; a1 += w001 * t001.y;
    a0 += w010 * t010.x; a1 += w010 * t010.y;
    a0 += w011 * t011.x; a1 += w011 * t011.y;
    a0 += w100 * t100.x; a1 += w100 * t100.y;
    a0 += w101 * t101.x; a1 += w101 * t101.y;
    a0 += w110 * t110.x; a1 += w110 * t110.y;
    a0 += w111 * t111.x; a1 += w111 * t111.y;

    enc16[(size_t)l * NPTS + p] = __floats2half2_rn(a0, a1);
}

// ---------------- kernel 3: MLPs + volrend scan ----------------
// __launch_bounds__(TPB, 1): NO artificial VGPR cap -> no scratch spill.
// Peak live state kept ~80 regs: f2[16] + h2a[64] (h1 is a scalar).
__global__ __launch_bounds__(TPB, 1) void mlp_kernel(
    const __half2* __restrict__ enc16,
    const float* __restrict__ delta,
    const float* __restrict__ w_in,
    const float* __restrict__ w_out,
    const float* __restrict__ rgb_w1,
    const float* __restrict__ rgb_w2,
    const float* __restrict__ rgb_w3,
    float* __restrict__ out)
{
    __shared__ float s_w_inT[64 * 32];   // [j][i]  (w_in is (32,64))
    __shared__ float s_w_out[64 * 16];   // [j][k]  as-is
    __shared__ float s_rgb_w1T[64 * 16]; // [j][i], padded 15->16 with 0
    __shared__ float s_rgb_w2[64 * 64];  // [j][k]  as-is
    __shared__ float s_rgb_w3[64 * 3];   // [j][c]  as-is
    __shared__ float s_wavetot[4];

    const int tid = threadIdx.x;
    // All LDS writes are linear in tid (conflict-free); transposes happen on the
    // global-read index (uncoalesced but tiny + L2-cached).
    for (int i = tid; i < 64 * 32; i += TPB) s_w_inT[i]   = w_in[(i & 31) * 64 + (i >> 5)];
    for (int i = tid; i < 64 * 16; i += TPB) s_w_out[i]   = w_out[i];
    for (int i = tid; i < 64 * 16; i += TPB) s_rgb_w1T[i] = ((i & 15) < 15) ? rgb_w1[(i & 15) * 64 + (i >> 4)] : 0.f;
    for (int i = tid; i < 64 * 64; i += TPB) s_rgb_w2[i]  = rgb_w2[i];
    for (int i = tid; i < 64 * 3;  i += TPB) s_rgb_w3[i]  = rgb_w3[i];
    __syncthreads();

    const int p = blockIdx.x * TPB + tid;

    float enc[32];
    #pragma unroll
    for (int l = 0; l < 16; ++l) {
        const float2 e = __half22float2(enc16[(size_t)l * NPTS + p]);
        enc[2 * l + 0] = e.x;
        enc[2 * l + 1] = e.y;
    }

    // layer1 (32->64, relu) fused with layer2 (64->16); h never stored
    float raw[16];
    #pragma unroll
    for (int k = 0; k < 16; ++k) raw[k] = 0.f;
    #pragma unroll
    for (int j = 0; j < 64; ++j) {
        const float4* wr = (const float4*)&s_w_inT[j * 32];
        float acc = 0.f;
        #pragma unroll
        for (int i = 0; i < 8; ++i) {
            const float4 w4 = wr[i];
            acc += w4.x * enc[4 * i + 0] + w4.y * enc[4 * i + 1]
                 + w4.z * enc[4 * i + 2] + w4.w * enc[4 * i + 3];
        }
        const float hj = fmaxf(acc, 0.f);
        const float4* wo = (const float4*)&s_w_out[j * 16];
        #pragma unroll
        for (int k = 0; k < 4; ++k) {
            const float4 w4 = wo[k];
            raw[4 * k + 0] += hj * w4.x;
            raw[4 * k + 1] += hj * w4.y;
            raw[4 * k + 2] += hj * w4.z;
            raw[4 * k + 3] += hj * w4.w;
        }
    }

    // volrend weights: per-ray scan over S=128 (2 waves per ray)
    const float dlt = delta[p];
    const float dd = expf(raw[0] + OFFSETC) * dlt;
    float v = dd;
    const int lane = tid & 63;
    #pragma unroll
    for (int d = 1; d < 64; d <<= 1) {
        const float n = __shfl_up(v, d, 64);
        if (lane >= d) v += n;
    }
    const int wv = tid >> 6;
    if (lane == 63) s_wavetot[wv] = v;
    __syncthreads();
    const float prev = (wv & 1) ? s_wavetot[wv - 1] : 0.f;
    const float excl = v - dd + prev;
    const float wgt = (1.f - expf(-dd)) * expf(-excl);

    // rgb MLP: f2(15) -> h1j scalar -> h2a[64] accum -> r0..r2
    float f2[16];
    #pragma unroll
    for (int i = 0; i < 15; ++i) f2[i] = raw[i + 1];
    f2[15] = 0.f;

    float h2a[64];
    #pragma unroll
    for (int k = 0; k < 64; ++k) h2a[k] = 0.f;
    #pragma unroll
    for (int j = 0; j < 64; ++j) {
        const float4* w1 = (const float4*)&s_rgb_w1T[j * 16];
        float acc = 0.f;
        #pragma unroll
        for (int i = 0; i < 4; ++i) {
            const float4 w4 = w1[i];
            acc += w4.x * f2[4 * i + 0] + w4.y * f2[4 * i + 1]
                 + w4.z * f2[4 * i + 2] + w4.w * f2[4 * i + 3];
        }
        const float h1j = fmaxf(acc, 0.f);
        const float4* w2 = (const float4*)&s_rgb_w2[j * 64];
        #pragma unroll
        for (int q = 0; q < 16; ++q) {
            const float4 w4 = w2[q];
            h2a[4 * q + 0] += h1j * w4.x;
            h2a[4 * q + 1] += h1j * w4.y;
            h2a[4 * q + 2] += h1j * w4.z;
            h2a[4 * q + 3] += h1j * w4.w;
        }
    }

    float r0 = 0.f, r1 = 0.f, r2 = 0.f;
    #pragma unroll
    for (int k = 0; k < 64; ++k) {
        const float h2k = fmaxf(h2a[k], 0.f);
        r0 += h2k * s_rgb_w3[k * 3 + 0];
        r1 += h2k * s_rgb_w3[k * 3 + 1];
        r2 += h2k * s_rgb_w3[k * 3 + 2];
    }
    const float s0 = 1.f / (1.f + expf(-r0));
    const float s1 = 1.f / (1.f + expf(-r1));
    const float s2 = 1.f / (1.f + expf(-r2));

    float4 o;
    o.x = wgt; o.y = s0; o.z = s1; o.w = s2;
    ((float4*)out)[p] = o;
}

// ---------------- fallback: fused kernel (used only if ws too small) ----------------
__global__ __launch_bounds__(TPB, 1) void density_field_fused(
    const float* __restrict__ xyz, const float* __restrict__ delta,
    const float* __restrict__ table, const float* __restrict__ w_in,
    const float* __restrict__ w_out, const float* __restrict__ rgb_w1,
    const float* __restrict__ rgb_w2, const float* __restrict__ rgb_w3,
    float* __restrict__ out)
{
    __shared__ float s_w_inT[64 * 32];
    __shared__ float s_w_out[64 * 16];
    __shared__ float s_rgb_w1T[64 * 16];
    __shared__ float s_rgb_w2[64 * 64];
    __shared__ float s_rgb_w3[64 * 3];
    __shared__ float s_wavetot[4];

    const int tid = threadIdx.x;
    for (int i = tid; i < 64 * 32; i += TPB) s_w_inT[i]   = w_in[(i & 31) * 64 + (i >> 5)];
    for (int i = tid; i < 64 * 16; i += TPB) s_w_out[i]   = w_out[i];
    for (int i = tid; i < 64 * 16; i += TPB) s_rgb_w1T[i] = ((i & 15) < 15) ? rgb_w1[(i & 15) * 64 + (i >> 4)] : 0.f;
    for (int i = tid; i < 64 * 64; i += TPB) s_rgb_w2[i]  = rgb_w2[i];
    for (int i = tid; i < 64 * 3;  i += TPB) s_rgb_w3[i]  = rgb_w3[i];
    __syncthreads();

    const int p = blockIdx.x * TPB + tid;
    const float x = xyz[3 * p + 0], y = xyz[3 * p + 1], z = xyz[3 * p + 2];

    float enc[32];
    #pragma unroll
    for (int l = 0; l < 16; ++l) {
        const float res = d_RES[l];
        const float px = x * res, py = y * res, pz = z * res;
        const float fx0 = floorf(px), fy0 = floorf(py), fz0 = floorf(pz);
        const float fx = px - fx0, fy = py - fy0, fz = pz - fz0;
        const unsigned ix = (unsigned)fx0, iy = (unsigned)fy0, iz = (unsigned)fz0;
        const unsigned hx0 = ix, hx1 = ix + 1u;
        const unsigned hy0 = iy * 2654435761u, hy1 = hy0 + 2654435761u;
        const unsigned hz0 = iz * 805459861u,  hz1 = hz0 + 805459861u;
        const float2* tab = (const float2*)table + ((size_t)l << 19);
        const float2 t000 = tab[(hx0 ^ hy0 ^ hz0) & HASH_MASK];
        const float2 t001 = tab[(hx0 ^ hy0 ^ hz1) & HASH_MASK];
        const float2 t010 = tab[(hx0 ^ hy1 ^ hz0) & HASH_MASK];
        const float2 t011 = tab[(hx0 ^ hy1 ^ hz1) & HASH_MASK];
        const float2 t100 = tab[(hx1 ^ hy0 ^ hz0) & HASH_MASK];
        const float2 t101 = tab[(hx1 ^ hy0 ^ hz1) & HASH_MASK];
        const float2 t110 = tab[(hx1 ^ hy1 ^ hz0) & HASH_MASK];
        const float2 t111 = tab[(hx1 ^ hy1 ^ hz1) & HASH_MASK];
        const float gx = 1.f - fx, gy = 1.f - fy, gz = 1.f - fz;
        const float w000 = gx * gy * gz, w001 = gx * gy * fz;
        const float w010 = gx * fy * gz, w011 = gx * fy * fz;
        const float w100 = fx * gy * gz, w101 = fx * gy * fz;
        const float w110 = fx * fy * gz, w111 = fx * fy * fz;
        float a0 = w000 * t000.x; float a1 = w000 * t000.y;
        a0 += w001 * t001.x; a1 += w001 * t001.y;
        a0 += w010 * t010.x; a1 += w010 * t010.y;
        a0 += w011 * t011.x; a1 += w011 * t011.y;
        a0 += w100 * t100.x; a1 += w100 * t100.y;
        a0 += w101 * t101.x; a1 += w101 * t101.y;
        a0 += w110 * t110.x; a1 += w110 * t110.y;
        a0 += w111 * t111.x; a1 += w111 * t111.y;
        enc[2 * l + 0] = a0; enc[2 * l + 1] = a1;
    }

    float raw[16];
    #pragma unroll
    for (int k = 0; k < 16; ++k) raw[k] = 0.f;
    #pragma unroll
    for (int j = 0; j < 64; ++j) {
        const float4* wr = (const float4*)&s_w_inT[j * 32];
        float acc = 0.f;
        #pragma unroll
        for (int i = 0; i < 8; ++i) {
            const float4 w4 = wr[i];
            acc += w4.x * enc[4 * i + 0] + w4.y * enc[4 * i + 1]
                 + w4.z * enc[4 * i + 2] + w4.w * enc[4 * i + 3];
        }
        const float hj = fmaxf(acc, 0.f);
        const float4* wo = (const float4*)&s_w_out[j * 16];
        #pragma unroll
        for (int k = 0; k < 4; ++k) {
            const float4 w4 = wo[k];
            raw[4 * k + 0] += hj * w4.x; raw[4 * k + 1] += hj * w4.y;
            raw[4 * k + 2] += hj * w4.z; raw[4 * k + 3] += hj * w4.w;
        }
    }

    const float dlt = delta[p];
    const float dd = expf(raw[0] + OFFSETC) * dlt;
    float v = dd;
    const int lane = tid & 63;
    #pragma unroll
    for (int d = 1; d < 64; d <<= 1) {
        const float n = __shfl_up(v, d, 64);
        if (lane >= d) v += n;
    }
    const int wv = tid >> 6;
    if (lane == 63) s_wavetot[wv] = v;
    __syncthreads();
    const float prev = (wv & 1) ? s_wavetot[wv - 1] : 0.f;
    const float excl = v - dd + prev;
    const float wgt = (1.f - expf(-dd)) * expf(-excl);

    float f2[16];
    #pragma unroll
    for (int i = 0; i < 15; ++i) f2[i] = raw[i + 1];
    f2[15] = 0.f;

    float h2a[64];
    #pragma unroll
    for (int k = 0; k < 64; ++k) h2a[k] = 0.f;
    #pragma unroll
    for (int j = 0; j < 64; ++j) {
        const float4* w1 = (const float4*)&s_rgb_w1T[j * 16];
        float acc = 0.f;
        #pragma unroll
        for (int i = 0; i < 4; ++i) {
            const float4 w4 = w1[i];
            acc += w4.x * f2[4 * i + 0] + w4.y * f2[4 * i + 1]
                 + w4.z * f2[4 * i + 2] + w4.w * f2[4 * i + 3];
        }
        const float h1j = fmaxf(acc, 0.f);
        const float4* w2 = (const float4*)&s_rgb_w2[j * 64];
        #pragma unroll
        for (int q = 0; q < 16; ++q) {
            const float4 w4 = w2[q];
            h2a[4 * q + 0] += h1j * w4.x;
            h2a[4 * q + 1] += h1j * w4.y;
            h2a[4 * q + 2] += h1j * w4.z;
            h2a[4 * q + 3] += h1j * w4.w;
        }
    }
    float r0 = 0.f, r1 = 0.f, r2 = 0.f;
    #pragma unroll
    for (int k = 0; k < 64; ++k) {
        const float h2k = fmaxf(h2a[k], 0.f);
        r0 += h2k * s_rgb_w3[k * 3 + 0];
        r1 += h2k * s_rgb_w3[k * 3 + 1];
        r2 += h2k * s_rgb_w3[k * 3 + 2];
    }
    const float s0 = 1.f / (1.f + expf(-r0));
    const float s1 = 1.f / (1.f + expf(-r1));
    const float s2 = 1.f / (1.f + expf(-r2));
    float4 o; o.x = wgt; o.y = s0; o.z = s1; o.w = s2;
    ((float4*)out)[p] = o;
}

extern "C" void kernel_launch(void* const* d_in, const int* in_sizes, int n_in,
                              void* d_out, int out_size, void* d_ws, size_t ws_size,
                              hipStream_t stream) {
    const float* xyz    = (const float*)d_in[0];
    const float* delta  = (const float*)d_in[1];
    const float* table  = (const float*)d_in[2];
    const float* w_in   = (const float*)d_in[3];
    const float* w_out  = (const float*)d_in[4];
    const float* rgb_w1 = (const float*)d_in[5];
    const float* rgb_w2 = (const float*)d_in[6];
    const float* rgb_w3 = (const float*)d_in[7];
    float* outp = (float*)d_out;

    if (ws_size >= TAB16_BYTES + ENC16_BYTES) {
        __half2* tab16 = (__half2*)d_ws;
        __half2* enc16 = (__half2*)((char*)d_ws + TAB16_BYTES);

        // 1) table f32 -> fp16   (one thread per entry: 16*2^19 = 8.4M entries)
        convert_table_kernel<<<(NLVL * HASHSZ) / TPB, TPB, 0, stream>>>(
            (const float2*)table, tab16);

        // 2) level-major encode: 16 levels * 2048 chunks = 32768 blocks
        encode_kernel<<<NLVL * (NPTS / TPB), TPB, 0, stream>>>(xyz, tab16, enc16);

        // 3) MLPs + scan
        mlp_kernel<<<NPTS / TPB, TPB, 0, stream>>>(
            enc16, delta, w_in, w_out, rgb_w1, rgb_w2, rgb_w3, outp);
    } else {
        density_field_fused<<<NPTS / TPB, TPB, 0, stream>>>(
            xyz, delta, table, w_in, w_out, rgb_w1, rgb_w2, rgb_w3, outp);
    }
}

// Round 17
// 633.302 us; speedup vs baseline: 5.3702x; 3.3561x over previous
//
#include <hip/hip_runtime.h>
#include <hip/hip_fp16.h>

#define TPB 256
static constexpr unsigned HASH_MASK = (1u << 19) - 1u;
// log(log(1/0.99)) - log(4.0) - 0.5
static constexpr float OFFSETC = -6.4864436218f;
static constexpr int NPTS = 4096 * 128;         // 524288 sample points
static constexpr int NLVL = 16;
static constexpr int HASHSZ = 1 << 19;

// ws layout: [0, 32MiB) fp16 table (level-major, __half2 per entry)
//            [32MiB, 64MiB) fp16 enc features enc16[l*NPTS + p] (__half2)
static constexpr size_t TAB16_BYTES = (size_t)NLVL * HASHSZ * sizeof(__half2); // 32 MiB
static constexpr size_t ENC16_BYTES = (size_t)NLVL * NPTS * sizeof(__half2);   // 32 MiB

__device__ __constant__ float d_RES[16] = {16.f, 23.f, 33.f, 48.f, 70.f, 101.f, 147.f, 212.f,
                                           307.f, 445.f, 645.f, 933.f, 1351.f, 1955.f, 2830.f, 4096.f};

// ---------------- kernel 1: f32 table -> fp16 table ----------------
__global__ __launch_bounds__(TPB) void convert_table_kernel(
    const float2* __restrict__ src, __half2* __restrict__ dst)
{
    const int i = blockIdx.x * TPB + threadIdx.x;   // one entry per thread
    const float2 v = src[i];
    dst[i] = __floats2half2_rn(v.x, v.y);
}

// ---------------- kernel 2: level-major hash encode ----------------
// bid = x + 8*(c + 2048*h); level = x + 8*h; chunk c covers points [c*256, c*256+256)
// bid % 8 == level % 8  ->  XCD x serves only levels {x, x+8} (4 MB fp16 = its L2)
__global__ __launch_bounds__(TPB, 8) void encode_kernel(
    const float* __restrict__ xyz,
    const __half2* __restrict__ tab16,
    __half2* __restrict__ enc16)
{
    const unsigned bid = blockIdx.x;
    const unsigned x = bid & 7u;
    const unsigned q = bid >> 3;
    const unsigned c = q & 2047u;
    const unsigned h = q >> 11;
    const int l = (int)(x + 8u * h);
    const int p = (int)(c * TPB + threadIdx.x);

    const float px0 = xyz[3 * p + 0];
    const float py0 = xyz[3 * p + 1];
    const float pz0 = xyz[3 * p + 2];

    const float res = d_RES[l];
    const float px = px0 * res, py = py0 * res, pz = pz0 * res;
    const float fx0 = floorf(px), fy0 = floorf(py), fz0 = floorf(pz);
    const float fx = px - fx0, fy = py - fy0, fz = pz - fz0;
    const unsigned ix = (unsigned)fx0, iy = (unsigned)fy0, iz = (unsigned)fz0;
    const unsigned hx0 = ix,               hx1 = ix + 1u;
    const unsigned hy0 = iy * 2654435761u, hy1 = hy0 + 2654435761u;
    const unsigned hz0 = iz * 805459861u,  hz1 = hz0 + 805459861u;
    const __half2* tab = tab16 + ((size_t)l << 19);
    const __half2 q000 = tab[(hx0 ^ hy0 ^ hz0) & HASH_MASK];
    const __half2 q001 = tab[(hx0 ^ hy0 ^ hz1) & HASH_MASK];
    const __half2 q010 = tab[(hx0 ^ hy1 ^ hz0) & HASH_MASK];
    const __half2 q011 = tab[(hx0 ^ hy1 ^ hz1) & HASH_MASK];
    const __half2 q100 = tab[(hx1 ^ hy0 ^ hz0) & HASH_MASK];
    const __half2 q101 = tab[(hx1 ^ hy0 ^ hz1) & HASH_MASK];
    const __half2 q110 = tab[(hx1 ^ hy1 ^ hz0) & HASH_MASK];
    const __half2 q111 = tab[(hx1 ^ hy1 ^ hz1) & HASH_MASK];
    const float2 t000 = __half22float2(q000), t001 = __half22float2(q001);
    const float2 t010 = __half22float2(q010), t011 = __half22float2(q011);
    const float2 t100 = __half22float2(q100), t101 = __half22float2(q101);
    const float2 t110 = __half22float2(q110), t111 = __half22float2(q111);
    const float gx = 1.f - fx, gy = 1.f - fy, gz = 1.f - fz;
    const float w000 = gx * gy * gz, w001 = gx * gy * fz;
    const float w010 = gx * fy * gz, w011 = gx * fy * fz;
    const float w100 = fx * gy * gz, w101 = fx * gy * fz;
    const float w110 = fx * fy * gz, w111 = fx * fy * fz;
    float a0 = w000 * t000.x; float a1 = w000 * t000.y;
    a0 += w001 * t001.x; a1 += w001 * t001.y;
    a0 += w010 * t010.x; a1 += w010 * t010.y;
    a0 += w011 * t011.x; a1 += w011 * t011.y;
    a0 += w100 * t100.x; a1 += w100 * t100.y;
    a0 += w101 * t101.x; a1 += w101 * t101.y;
    a0 += w110 * t110.x; a1 += w110 * t110.y;
    a0 += w111 * t111.x; a1 += w111 * t111.y;

    enc16[(size_t)l * NPTS + p] = __floats2half2_rn(a0, a1);
}

// ---------------- kernel 3: MLPs + volrend scan ----------------
// __launch_bounds__(TPB, 1): no artificial VGPR cap.
// KEY: the 64-iteration loops are only unroll-2 — full unroll made the
// scheduler hoist ~1000 LDS loads and spill past even 256 VGPRs (round 13:
// VGPR=256, WRITE 2.6 GB scratch). Rolled loops bound live state to ~130 regs.
// All array indices inside are compile-time constants -> arrays stay in regs.
__global__ __launch_bounds__(TPB, 1) void mlp_kernel(
    const __half2* __restrict__ enc16,
    const float* __restrict__ delta,
    const float* __restrict__ w_in,
    const float* __restrict__ w_out,
    const float* __restrict__ rgb_w1,
    const float* __restrict__ rgb_w2,
    const float* __restrict__ rgb_w3,
    float* __restrict__ out)
{
    __shared__ float s_w_inT[64 * 32];   // [j][i]  (w_in is (32,64))
    __shared__ float s_w_out[64 * 16];   // [j][k]  as-is
    __shared__ float s_rgb_w1T[64 * 16]; // [j][i], padded 15->16 with 0
    __shared__ float s_rgb_w2[64 * 64];  // [j][k]  as-is
    __shared__ float s_rgb_w3[64 * 3];   // [j][c]  as-is
    __shared__ float s_wavetot[4];

    const int tid = threadIdx.x;
    // LDS writes linear in tid (conflict-free); transpose on the global-read index.
    for (int i = tid; i < 64 * 32; i += TPB) s_w_inT[i]   = w_in[(i & 31) * 64 + (i >> 5)];
    for (int i = tid; i < 64 * 16; i += TPB) s_w_out[i]   = w_out[i];
    for (int i = tid; i < 64 * 16; i += TPB) s_rgb_w1T[i] = ((i & 15) < 15) ? rgb_w1[(i & 15) * 64 + (i >> 4)] : 0.f;
    for (int i = tid; i < 64 * 64; i += TPB) s_rgb_w2[i]  = rgb_w2[i];
    for (int i = tid; i < 64 * 3;  i += TPB) s_rgb_w3[i]  = rgb_w3[i];
    __syncthreads();

    const int p = blockIdx.x * TPB + tid;

    float enc[32];
    #pragma unroll
    for (int l = 0; l < 16; ++l) {
        const float2 e = __half22float2(enc16[(size_t)l * NPTS + p]);
        enc[2 * l + 0] = e.x;
        enc[2 * l + 1] = e.y;
    }

    // layer1 (32->64, relu) fused with layer2 (64->16); h never stored
    float raw[16];
    #pragma unroll
    for (int k = 0; k < 16; ++k) raw[k] = 0.f;
    #pragma unroll 2
    for (int j = 0; j < 64; ++j) {
        const float4* wr = (const float4*)&s_w_inT[j * 32];
        float acc = 0.f;
        #pragma unroll
        for (int i = 0; i < 8; ++i) {
            const float4 w4 = wr[i];
            acc += w4.x * enc[4 * i + 0] + w4.y * enc[4 * i + 1]
                 + w4.z * enc[4 * i + 2] + w4.w * enc[4 * i + 3];
        }
        const float hj = fmaxf(acc, 0.f);
        const float4* wo = (const float4*)&s_w_out[j * 16];
        #pragma unroll
        for (int k = 0; k < 4; ++k) {
            const float4 w4 = wo[k];
            raw[4 * k + 0] += hj * w4.x;
            raw[4 * k + 1] += hj * w4.y;
            raw[4 * k + 2] += hj * w4.z;
            raw[4 * k + 3] += hj * w4.w;
        }
    }

    // volrend weights: per-ray scan over S=128 (2 waves per ray)
    const float dlt = delta[p];
    const float dd = expf(raw[0] + OFFSETC) * dlt;
    float v = dd;
    const int lane = tid & 63;
    #pragma unroll
    for (int d = 1; d < 64; d <<= 1) {
        const float n = __shfl_up(v, d, 64);
        if (lane >= d) v += n;
    }
    const int wv = tid >> 6;
    if (lane == 63) s_wavetot[wv] = v;
    __syncthreads();
    const float prev = (wv & 1) ? s_wavetot[wv - 1] : 0.f;
    const float excl = v - dd + prev;
    const float wgt = (1.f - expf(-dd)) * expf(-excl);

    // rgb MLP: f2(15) -> h1j scalar -> h2a[64] accum -> r0..r2
    float f2[16];
    #pragma unroll
    for (int i = 0; i < 15; ++i) f2[i] = raw[i + 1];
    f2[15] = 0.f;

    float h2a[64];
    #pragma unroll
    for (int k = 0; k < 64; ++k) h2a[k] = 0.f;
    #pragma unroll 2
    for (int j = 0; j < 64; ++j) {
        const float4* w1 = (const float4*)&s_rgb_w1T[j * 16];
        float acc = 0.f;
        #pragma unroll
        for (int i = 0; i < 4; ++i) {
            const float4 w4 = w1[i];
            acc += w4.x * f2[4 * i + 0] + w4.y * f2[4 * i + 1]
                 + w4.z * f2[4 * i + 2] + w4.w * f2[4 * i + 3];
        }
        const float h1j = fmaxf(acc, 0.f);
        const float4* w2 = (const float4*)&s_rgb_w2[j * 64];
        #pragma unroll
        for (int q = 0; q < 16; ++q) {
            const float4 w4 = w2[q];
            h2a[4 * q + 0] += h1j * w4.x;
            h2a[4 * q + 1] += h1j * w4.y;
            h2a[4 * q + 2] += h1j * w4.z;
            h2a[4 * q + 3] += h1j * w4.w;
        }
    }

    float r0 = 0.f, r1 = 0.f, r2 = 0.f;
    #pragma unroll 4
    for (int k = 0; k < 64; ++k) {
        const float h2k = fmaxf(h2a[k], 0.f);
        r0 += h2k * s_rgb_w3[k * 3 + 0];
        r1 += h2k * s_rgb_w3[k * 3 + 1];
        r2 += h2k * s_rgb_w3[k * 3 + 2];
    }
    const float s0 = 1.f / (1.f + expf(-r0));
    const float s1 = 1.f / (1.f + expf(-r1));
    const float s2 = 1.f / (1.f + expf(-r2));

    float4 o;
    o.x = wgt; o.y = s0; o.z = s1; o.w = s2;
    ((float4*)out)[p] = o;
}

// ---------------- fallback: fused kernel (used only if ws too small) ----------------
__global__ __launch_bounds__(TPB, 1) void density_field_fused(
    const float* __restrict__ xyz, const float* __restrict__ delta,
    const float* __restrict__ table, const float* __restrict__ w_in,
    const float* __restrict__ w_out, const float* __restrict__ rgb_w1,
    const float* __restrict__ rgb_w2, const float* __restrict__ rgb_w3,
    float* __restrict__ out)
{
    __shared__ float s_w_inT[64 * 32];
    __shared__ float s_w_out[64 * 16];
    __shared__ float s_rgb_w1T[64 * 16];
    __shared__ float s_rgb_w2[64 * 64];
    __shared__ float s_rgb_w3[64 * 3];
    __shared__ float s_wavetot[4];

    const int tid = threadIdx.x;
    for (int i = tid; i < 64 * 32; i += TPB) s_w_inT[i]   = w_in[(i & 31) * 64 + (i >> 5)];
    for (int i = tid; i < 64 * 16; i += TPB) s_w_out[i]   = w_out[i];
    for (int i = tid; i < 64 * 16; i += TPB) s_rgb_w1T[i] = ((i & 15) < 15) ? rgb_w1[(i & 15) * 64 + (i >> 4)] : 0.f;
    for (int i = tid; i < 64 * 64; i += TPB) s_rgb_w2[i]  = rgb_w2[i];
    for (int i = tid; i < 64 * 3;  i += TPB) s_rgb_w3[i]  = rgb_w3[i];
    __syncthreads();

    const int p = blockIdx.x * TPB + tid;
    const float x = xyz[3 * p + 0], y = xyz[3 * p + 1], z = xyz[3 * p + 2];

    float enc[32];
    #pragma unroll 2
    for (int l = 0; l < 16; ++l) {
        const float res = d_RES[l];
        const float px = x * res, py = y * res, pz = z * res;
        const float fx0 = floorf(px), fy0 = floorf(py), fz0 = floorf(pz);
        const float fx = px - fx0, fy = py - fy0, fz = pz - fz0;
        const unsigned ix = (unsigned)fx0, iy = (unsigned)fy0, iz = (unsigned)fz0;
        const unsigned hx0 = ix, hx1 = ix + 1u;
        const unsigned hy0 = iy * 2654435761u, hy1 = hy0 + 2654435761u;
        const unsigned hz0 = iz * 805459861u,  hz1 = hz0 + 805459861u;
        const float2* tab = (const float2*)table + ((size_t)l << 19);
        const float2 t000 = tab[(hx0 ^ hy0 ^ hz0) & HASH_MASK];
        const float2 t001 = tab[(hx0 ^ hy0 ^ hz1) & HASH_MASK];
        const float2 t010 = tab[(hx0 ^ hy1 ^ hz0) & HASH_MASK];
        const float2 t011 = tab[(hx0 ^ hy1 ^ hz1) & HASH_MASK];
        const float2 t100 = tab[(hx1 ^ hy0 ^ hz0) & HASH_MASK];
        const float2 t101 = tab[(hx1 ^ hy0 ^ hz1) & HASH_MASK];
        const float2 t110 = tab[(hx1 ^ hy1 ^ hz0) & HASH_MASK];
        const float2 t111 = tab[(hx1 ^ hy1 ^ hz1) & HASH_MASK];
        const float gx = 1.f - fx, gy = 1.f - fy, gz = 1.f - fz;
        const float w000 = gx * gy * gz, w001 = gx * gy * fz;
        const float w010 = gx * fy * gz, w011 = gx * fy * fz;
        const float w100 = fx * gy * gz, w101 = fx * gy * fz;
        const float w110 = fx * fy * gz, w111 = fx * fy * fz;
        float a0 = w000 * t000.x; float a1 = w000 * t000.y;
        a0 += w001 * t001.x; a1 += w001 * t001.y;
        a0 += w010 * t010.x; a1 += w010 * t010.y;
        a0 += w011 * t011.x; a1 += w011 * t011.y;
        a0 += w100 * t100.x; a1 += w100 * t100.y;
        a0 += w101 * t101.x; a1 += w101 * t101.y;
        a0 += w110 * t110.x; a1 += w110 * t110.y;
        a0 += w111 * t111.x; a1 += w111 * t111.y;
        enc[2 * l + 0] = a0; enc[2 * l + 1] = a1;
    }

    float raw[16];
    #pragma unroll
    for (int k = 0; k < 16; ++k) raw[k] = 0.f;
    #pragma unroll 2
    for (int j = 0; j < 64; ++j) {
        const float4* wr = (const float4*)&s_w_inT[j * 32];
        float acc = 0.f;
        #pragma unroll
        for (int i = 0; i < 8; ++i) {
            const float4 w4 = wr[i];
            acc += w4.x * enc[4 * i + 0] + w4.y * enc[4 * i + 1]
                 + w4.z * enc[4 * i + 2] + w4.w * enc[4 * i + 3];
        }
        const float hj = fmaxf(acc, 0.f);
        const float4* wo = (const float4*)&s_w_out[j * 16];
        #pragma unroll
        for (int k = 0; k < 4; ++k) {
            const float4 w4 = wo[k];
            raw[4 * k + 0] += hj * w4.x; raw[4 * k + 1] += hj * w4.y;
            raw[4 * k + 2] += hj * w4.z; raw[4 * k + 3] += hj * w4.w;
        }
    }

    const float dlt = delta[p];
    const float dd = expf(raw[0] + OFFSETC) * dlt;
    float v = dd;
    const int lane = tid & 63;
    #pragma unroll
    for (int d = 1; d < 64; d <<= 1) {
        const float n = __shfl_up(v, d, 64);
        if (lane >= d) v += n;
    }
    const int wv = tid >> 6;
    if (lane == 63) s_wavetot[wv] = v;
    __syncthreads();
    const float prev = (wv & 1) ? s_wavetot[wv - 1] : 0.f;
    const float excl = v - dd + prev;
    const float wgt = (1.f - expf(-dd)) * expf(-excl);

    float f2[16];
    #pragma unroll
    for (int i = 0; i < 15; ++i) f2[i] = raw[i + 1];
    f2[15] = 0.f;

    float h2a[64];
    #pragma unroll
    for (int k = 0; k < 64; ++k) h2a[k] = 0.f;
    #pragma unroll 2
    for (int j = 0; j < 64; ++j) {
        const float4* w1 = (const float4*)&s_rgb_w1T[j * 16];
        float acc = 0.f;
        #pragma unroll
        for (int i = 0; i < 4; ++i) {
            const float4 w4 = w1[i];
            acc += w4.x * f2[4 * i + 0] + w4.y * f2[4 * i + 1]
                 + w4.z * f2[4 * i + 2] + w4.w * f2[4 * i + 3];
        }
        const float h1j = fmaxf(acc, 0.f);
        const float4* w2 = (const float4*)&s_rgb_w2[j * 64];
        #pragma unroll
        for (int q = 0; q < 16; ++q) {
            const float4 w4 = w2[q];
            h2a[4 * q + 0] += h1j * w4.x;
            h2a[4 * q + 1] += h1j * w4.y;
            h2a[4 * q + 2] += h1j * w4.z;
            h2a[4 * q + 3] += h1j * w4.w;
        }
    }
    float r0 = 0.f, r1 = 0.f, r2 = 0.f;
    #pragma unroll 4
    for (int k = 0; k < 64; ++k) {
        const float h2k = fmaxf(h2a[k], 0.f);
        r0 += h2k * s_rgb_w3[k * 3 + 0];
        r1 += h2k * s_rgb_w3[k * 3 + 1];
        r2 += h2k * s_rgb_w3[k * 3 + 2];
    }
    const float s0 = 1.f / (1.f + expf(-r0));
    const float s1 = 1.f / (1.f + expf(-r1));
    const float s2 = 1.f / (1.f + expf(-r2));
    float4 o; o.x = wgt; o.y = s0; o.z = s1; o.w = s2;
    ((float4*)out)[p] = o;
}

extern "C" void kernel_launch(void* const* d_in, const int* in_sizes, int n_in,
                              void* d_out, int out_size, void* d_ws, size_t ws_size,
                              hipStream_t stream) {
    const float* xyz    = (const float*)d_in[0];
    const float* delta  = (const float*)d_in[1];
    const float* table  = (const float*)d_in[2];
    const float* w_in   = (const float*)d_in[3];
    const float* w_out  = (const float*)d_in[4];
    const float* rgb_w1 = (const float*)d_in[5];
    const float* rgb_w2 = (const float*)d_in[6];
    const float* rgb_w3 = (const float*)d_in[7];
    float* outp = (float*)d_out;

    if (ws_size >= TAB16_BYTES + ENC16_BYTES) {
        __half2* tab16 = (__half2*)d_ws;
        __half2* enc16 = (__half2*)((char*)d_ws + TAB16_BYTES);

        // 1) table f32 -> fp16   (one thread per entry: 16*2^19 = 8.4M entries)
        convert_table_kernel<<<(NLVL * HASHSZ) / TPB, TPB, 0, stream>>>(
            (const float2*)table, tab16);

        // 2) level-major encode: 16 levels * 2048 chunks = 32768 blocks
        encode_kernel<<<NLVL * (NPTS / TPB), TPB, 0, stream>>>(xyz, tab16, enc16);

        // 3) MLPs + scan
        mlp_kernel<<<NPTS / TPB, TPB, 0, stream>>>(
            enc16, delta, w_in, w_out, rgb_w1, rgb_w2, rgb_w3, outp);
    } else {
        density_field_fused<<<NPTS / TPB, TPB, 0, stream>>>(
            xyz, delta, table, w_in, w_out, rgb_w1, rgb_w2, rgb_w3, outp);
    }
}

// Round 18
// 599.575 us; speedup vs baseline: 5.6723x; 1.0563x over previous
//
#include <hip/hip_runtime.h>
#include <hip/hip_fp16.h>

#define TPB 256
static constexpr unsigned HASH_MASK = (1u << 19) - 1u;
// log(log(1/0.99)) - log(4.0) - 0.5
static constexpr float OFFSETC = -6.4864436218f;
static constexpr int NPTS = 4096 * 128;         // 524288 sample points
static constexpr int NLVL = 16;
static constexpr int HASHSZ = 1 << 19;

// ws layout: [0, 32MiB) fp16 table (level-major, __half2 per entry)
//            [32MiB, 64MiB) fp16 enc features enc16[l*NPTS + p] (__half2)
static constexpr size_t TAB16_BYTES = (size_t)NLVL * HASHSZ * sizeof(__half2); // 32 MiB
static constexpr size_t ENC16_BYTES = (size_t)NLVL * NPTS * sizeof(__half2);   // 32 MiB

__device__ __constant__ float d_RES[16] = {16.f, 23.f, 33.f, 48.f, 70.f, 101.f, 147.f, 212.f,
                                           307.f, 445.f, 645.f, 933.f, 1351.f, 1955.f, 2830.f, 4096.f};

// ---------------- kernel 1: f32 table -> fp16 table ----------------
__global__ __launch_bounds__(TPB) void convert_table_kernel(
    const float2* __restrict__ src, __half2* __restrict__ dst)
{
    const int i = blockIdx.x * TPB + threadIdx.x;   // one entry per thread
    const float2 v = src[i];
    dst[i] = __floats2half2_rn(v.x, v.y);
}

// ---------------- kernel 2: level-major hash encode ----------------
// bid = x + 8*(c + 2048*h); level = x + 8*h; chunk c covers points [c*256, c*256+256)
// bid % 8 == level % 8  ->  XCD x serves only levels {x, x+8} (4 MB fp16 = its L2)
__global__ __launch_bounds__(TPB, 8) void encode_kernel(
    const float* __restrict__ xyz,
    const __half2* __restrict__ tab16,
    __half2* __restrict__ enc16)
{
    const unsigned bid = blockIdx.x;
    const unsigned x = bid & 7u;
    const unsigned q = bid >> 3;
    const unsigned c = q & 2047u;
    const unsigned h = q >> 11;
    const int l = (int)(x + 8u * h);
    const int p = (int)(c * TPB + threadIdx.x);

    const float px0 = xyz[3 * p + 0];
    const float py0 = xyz[3 * p + 1];
    const float pz0 = xyz[3 * p + 2];

    const float res = d_RES[l];
    const float px = px0 * res, py = py0 * res, pz = pz0 * res;
    const float fx0 = floorf(px), fy0 = floorf(py), fz0 = floorf(pz);
    const float fx = px - fx0, fy = py - fy0, fz = pz - fz0;
    const unsigned ix = (unsigned)fx0, iy = (unsigned)fy0, iz = (unsigned)fz0;
    const unsigned hx0 = ix,               hx1 = ix + 1u;
    const unsigned hy0 = iy * 2654435761u, hy1 = hy0 + 2654435761u;
    const unsigned hz0 = iz * 805459861u,  hz1 = hz0 + 805459861u;
    const __half2* tab = tab16 + ((size_t)l << 19);
    const __half2 q000 = tab[(hx0 ^ hy0 ^ hz0) & HASH_MASK];
    const __half2 q001 = tab[(hx0 ^ hy0 ^ hz1) & HASH_MASK];
    const __half2 q010 = tab[(hx0 ^ hy1 ^ hz0) & HASH_MASK];
    const __half2 q011 = tab[(hx0 ^ hy1 ^ hz1) & HASH_MASK];
    const __half2 q100 = tab[(hx1 ^ hy0 ^ hz0) & HASH_MASK];
    const __half2 q101 = tab[(hx1 ^ hy0 ^ hz1) & HASH_MASK];
    const __half2 q110 = tab[(hx1 ^ hy1 ^ hz0) & HASH_MASK];
    const __half2 q111 = tab[(hx1 ^ hy1 ^ hz1) & HASH_MASK];
    const float2 t000 = __half22float2(q000), t001 = __half22float2(q001);
    const float2 t010 = __half22float2(q010), t011 = __half22float2(q011);
    const float2 t100 = __half22float2(q100), t101 = __half22float2(q101);
    const float2 t110 = __half22float2(q110), t111 = __half22float2(q111);
    const float gx = 1.f - fx, gy = 1.f - fy, gz = 1.f - fz;
    const float w000 = gx * gy * gz, w001 = gx * gy * fz;
    const float w010 = gx * fy * gz, w011 = gx * fy * fz;
    const float w100 = fx * gy * gz, w101 = fx * gy * fz;
    const float w110 = fx * fy * gz, w111 = fx * fy * fz;
    float a0 = w000 * t000.x; float a1 = w000 * t000.y;
    a0 += w001 * t001.x; a1 += w001 * t001.y;
    a0 += w010 * t010.x; a1 += w010 * t010.y;
    a0 += w011 * t011.x; a1 += w011 * t011.y;
    a0 += w100 * t100.x; a1 += w100 * t100.y;
    a0 += w101 * t101.x; a1 += w101 * t101.y;
    a0 += w110 * t110.x; a1 += w110 * t110.y;
    a0 += w111 * t111.x; a1 += w111 * t111.y;

    enc16[(size_t)l * NPTS + p] = __floats2half2_rn(a0, a1);
}

// ---------------- kernel 3: MLPs + volrend scan ----------------
// __launch_bounds__(TPB, 1): no artificial VGPR cap.
// 64-iter MLP loops: unroll-2 (full unroll hoists ~1000 LDS loads -> spill,
// round 13). Final reduction loop: FULL unroll, because a runtime index into
// h2a[] demotes the whole array to scratch (round 17: VGPR=72, WRITE 258 MB).
// All array accesses are compile-time-indexed -> enc/raw/f2/h2a live in regs.
__global__ __launch_bounds__(TPB, 1) void mlp_kernel(
    const __half2* __restrict__ enc16,
    const float* __restrict__ delta,
    const float* __restrict__ w_in,
    const float* __restrict__ w_out,
    const float* __restrict__ rgb_w1,
    const float* __restrict__ rgb_w2,
    const float* __restrict__ rgb_w3,
    float* __restrict__ out)
{
    __shared__ float s_w_inT[64 * 32];   // [j][i]  (w_in is (32,64))
    __shared__ float s_w_out[64 * 16];   // [j][k]  as-is
    __shared__ float s_rgb_w1T[64 * 16]; // [j][i], padded 15->16 with 0
    __shared__ float s_rgb_w2[64 * 64];  // [j][k]  as-is
    __shared__ float s_rgb_w3[64 * 3];   // [j][c]  as-is
    __shared__ float s_wavetot[4];

    const int tid = threadIdx.x;
    // LDS writes linear in tid (conflict-free); transpose on the global-read index.
    for (int i = tid; i < 64 * 32; i += TPB) s_w_inT[i]   = w_in[(i & 31) * 64 + (i >> 5)];
    for (int i = tid; i < 64 * 16; i += TPB) s_w_out[i]   = w_out[i];
    for (int i = tid; i < 64 * 16; i += TPB) s_rgb_w1T[i] = ((i & 15) < 15) ? rgb_w1[(i & 15) * 64 + (i >> 4)] : 0.f;
    for (int i = tid; i < 64 * 64; i += TPB) s_rgb_w2[i]  = rgb_w2[i];
    for (int i = tid; i < 64 * 3;  i += TPB) s_rgb_w3[i]  = rgb_w3[i];
    __syncthreads();

    const int p = blockIdx.x * TPB + tid;

    float enc[32];
    #pragma unroll
    for (int l = 0; l < 16; ++l) {
        const float2 e = __half22float2(enc16[(size_t)l * NPTS + p]);
        enc[2 * l + 0] = e.x;
        enc[2 * l + 1] = e.y;
    }

    // layer1 (32->64, relu) fused with layer2 (64->16); h never stored
    float raw[16];
    #pragma unroll
    for (int k = 0; k < 16; ++k) raw[k] = 0.f;
    #pragma unroll 2
    for (int j = 0; j < 64; ++j) {
        const float4* wr = (const float4*)&s_w_inT[j * 32];
        float acc = 0.f;
        #pragma unroll
        for (int i = 0; i < 8; ++i) {
            const float4 w4 = wr[i];
            acc += w4.x * enc[4 * i + 0] + w4.y * enc[4 * i + 1]
                 + w4.z * enc[4 * i + 2] + w4.w * enc[4 * i + 3];
        }
        const float hj = fmaxf(acc, 0.f);
        const float4* wo = (const float4*)&s_w_out[j * 16];
        #pragma unroll
        for (int k = 0; k < 4; ++k) {
            const float4 w4 = wo[k];
            raw[4 * k + 0] += hj * w4.x;
            raw[4 * k + 1] += hj * w4.y;
            raw[4 * k + 2] += hj * w4.z;
            raw[4 * k + 3] += hj * w4.w;
        }
    }

    // volrend weights: per-ray scan over S=128 (2 waves per ray)
    const float dlt = delta[p];
    const float dd = expf(raw[0] + OFFSETC) * dlt;
    float v = dd;
    const int lane = tid & 63;
    #pragma unroll
    for (int d = 1; d < 64; d <<= 1) {
        const float n = __shfl_up(v, d, 64);
        if (lane >= d) v += n;
    }
    const int wv = tid >> 6;
    if (lane == 63) s_wavetot[wv] = v;
    __syncthreads();
    const float prev = (wv & 1) ? s_wavetot[wv - 1] : 0.f;
    const float excl = v - dd + prev;
    const float wgt = (1.f - expf(-dd)) * expf(-excl);

    // rgb MLP: f2(15) -> h1j scalar -> h2a[64] accum -> r0..r2
    float f2[16];
    #pragma unroll
    for (int i = 0; i < 15; ++i) f2[i] = raw[i + 1];
    f2[15] = 0.f;

    float h2a[64];
    #pragma unroll
    for (int k = 0; k < 64; ++k) h2a[k] = 0.f;
    #pragma unroll 2
    for (int j = 0; j < 64; ++j) {
        const float4* w1 = (const float4*)&s_rgb_w1T[j * 16];
        float acc = 0.f;
        #pragma unroll
        for (int i = 0; i < 4; ++i) {
            const float4 w4 = w1[i];
            acc += w4.x * f2[4 * i + 0] + w4.y * f2[4 * i + 1]
                 + w4.z * f2[4 * i + 2] + w4.w * f2[4 * i + 3];
        }
        const float h1j = fmaxf(acc, 0.f);
        const float4* w2 = (const float4*)&s_rgb_w2[j * 64];
        #pragma unroll
        for (int q = 0; q < 16; ++q) {
            const float4 w4 = w2[q];
            h2a[4 * q + 0] += h1j * w4.x;
            h2a[4 * q + 1] += h1j * w4.y;
            h2a[4 * q + 2] += h1j * w4.z;
            h2a[4 * q + 3] += h1j * w4.w;
        }
    }

    // FULL unroll: h2a[k] must be compile-time-indexed or the array demotes
    // to scratch (rule #20; round-17 counters showed exactly that).
    float r0 = 0.f, r1 = 0.f, r2 = 0.f;
    #pragma unroll
    for (int k = 0; k < 64; ++k) {
        const float h2k = fmaxf(h2a[k], 0.f);
        r0 += h2k * s_rgb_w3[k * 3 + 0];
        r1 += h2k * s_rgb_w3[k * 3 + 1];
        r2 += h2k * s_rgb_w3[k * 3 + 2];
    }
    const float s0 = 1.f / (1.f + expf(-r0));
    const float s1 = 1.f / (1.f + expf(-r1));
    const float s2 = 1.f / (1.f + expf(-r2));

    float4 o;
    o.x = wgt; o.y = s0; o.z = s1; o.w = s2;
    ((float4*)out)[p] = o;
}

// ---------------- fallback: fused kernel (used only if ws too small) ----------------
__global__ __launch_bounds__(TPB, 1) void density_field_fused(
    const float* __restrict__ xyz, const float* __restrict__ delta,
    const float* __restrict__ table, const float* __restrict__ w_in,
    const float* __restrict__ w_out, const float* __restrict__ rgb_w1,
    const float* __restrict__ rgb_w2, const float* __restrict__ rgb_w3,
    float* __restrict__ out)
{
    __shared__ float s_w_inT[64 * 32];
    __shared__ float s_w_out[64 * 16];
    __shared__ float s_rgb_w1T[64 * 16];
    __shared__ float s_rgb_w2[64 * 64];
    __shared__ float s_rgb_w3[64 * 3];
    __shared__ float s_wavetot[4];

    const int tid = threadIdx.x;
    for (int i = tid; i < 64 * 32; i += TPB) s_w_inT[i]   = w_in[(i & 31) * 64 + (i >> 5)];
    for (int i = tid; i < 64 * 16; i += TPB) s_w_out[i]   = w_out[i];
    for (int i = tid; i < 64 * 16; i += TPB) s_rgb_w1T[i] = ((i & 15) < 15) ? rgb_w1[(i & 15) * 64 + (i >> 4)] : 0.f;
    for (int i = tid; i < 64 * 64; i += TPB) s_rgb_w2[i]  = rgb_w2[i];
    for (int i = tid; i < 64 * 3;  i += TPB) s_rgb_w3[i]  = rgb_w3[i];
    __syncthreads();

    const int p = blockIdx.x * TPB + tid;
    const float x = xyz[3 * p + 0], y = xyz[3 * p + 1], z = xyz[3 * p + 2];

    float enc[32];
    #pragma unroll 2
    for (int l = 0; l < 16; ++l) {
        const float res = d_RES[l];
        const float px = x * res, py = y * res, pz = z * res;
        const float fx0 = floorf(px), fy0 = floorf(py), fz0 = floorf(pz);
        const float fx = px - fx0, fy = py - fy0, fz = pz - fz0;
        const unsigned ix = (unsigned)fx0, iy = (unsigned)fy0, iz = (unsigned)fz0;
        const unsigned hx0 = ix, hx1 = ix + 1u;
        const unsigned hy0 = iy * 2654435761u, hy1 = hy0 + 2654435761u;
        const unsigned hz0 = iz * 805459861u,  hz1 = hz0 + 805459861u;
        const float2* tab = (const float2*)table + ((size_t)l << 19);
        const float2 t000 = tab[(hx0 ^ hy0 ^ hz0) & HASH_MASK];
        const float2 t001 = tab[(hx0 ^ hy0 ^ hz1) & HASH_MASK];
        const float2 t010 = tab[(hx0 ^ hy1 ^ hz0) & HASH_MASK];
        const float2 t011 = tab[(hx0 ^ hy1 ^ hz1) & HASH_MASK];
        const float2 t100 = tab[(hx1 ^ hy0 ^ hz0) & HASH_MASK];
        const float2 t101 = tab[(hx1 ^ hy0 ^ hz1) & HASH_MASK];
        const float2 t110 = tab[(hx1 ^ hy1 ^ hz0) & HASH_MASK];
        const float2 t111 = tab[(hx1 ^ hy1 ^ hz1) & HASH_MASK];
        const float gx = 1.f - fx, gy = 1.f - fy, gz = 1.f - fz;
        const float w000 = gx * gy * gz, w001 = gx * gy * fz;
        const float w010 = gx * fy * gz, w011 = gx * fy * fz;
        const float w100 = fx * gy * gz, w101 = fx * gy * fz;
        const float w110 = fx * fy * gz, w111 = fx * fy * fz;
        float a0 = w000 * t000.x; float a1 = w000 * t000.y;
        a0 += w001 * t001.x; a1 += w001 * t001.y;
        a0 += w010 * t010.x; a1 += w010 * t010.y;
        a0 += w011 * t011.x; a1 += w011 * t011.y;
        a0 += w100 * t100.x; a1 += w100 * t100.y;
        a0 += w101 * t101.x; a1 += w101 * t101.y;
        a0 += w110 * t110.x; a1 += w110 * t110.y;
        a0 += w111 * t111.x; a1 += w111 * t111.y;
        enc[2 * l + 0] = a0; enc[2 * l + 1] = a1;
    }

    float raw[16];
    #pragma unroll
    for (int k = 0; k < 16; ++k) raw[k] = 0.f;
    #pragma unroll 2
    for (int j = 0; j < 64; ++j) {
        const float4* wr = (const float4*)&s_w_inT[j * 32];
        float acc = 0.f;
        #pragma unroll
        for (int i = 0; i < 8; ++i) {
            const float4 w4 = wr[i];
            acc += w4.x * enc[4 * i + 0] + w4.y * enc[4 * i + 1]
                 + w4.z * enc[4 * i + 2] + w4.w * enc[4 * i + 3];
        }
        const float hj = fmaxf(acc, 0.f);
        const float4* wo = (const float4*)&s_w_out[j * 16];
        #pragma unroll
        for (int k = 0; k < 4; ++k) {
            const float4 w4 = wo[k];
            raw[4 * k + 0] += hj * w4.x; raw[4 * k + 1] += hj * w4.y;
            raw[4 * k + 2] += hj * w4.z; raw[4 * k + 3] += hj * w4.w;
        }
    }

    const float dlt = delta[p];
    const float dd = expf(raw[0] + OFFSETC) * dlt;
    float v = dd;
    const int lane = tid & 63;
    #pragma unroll
    for (int d = 1; d < 64; d <<= 1) {
        const float n = __shfl_up(v, d, 64);
        if (lane >= d) v += n;
    }
    const int wv = tid >> 6;
    if (lane == 63) s_wavetot[wv] = v;
    __syncthreads();
    const float prev = (wv & 1) ? s_wavetot[wv - 1] : 0.f;
    const float excl = v - dd + prev;
    const float wgt = (1.f - expf(-dd)) * expf(-excl);

    float f2[16];
    #pragma unroll
    for (int i = 0; i < 15; ++i) f2[i] = raw[i + 1];
    f2[15] = 0.f;

    float h2a[64];
    #pragma unroll
    for (int k = 0; k < 64; ++k) h2a[k] = 0.f;
    #pragma unroll 2
    for (int j = 0; j < 64; ++j) {
        const float4* w1 = (const float4*)&s_rgb_w1T[j * 16];
        float acc = 0.f;
        #pragma unroll
        for (int i = 0; i < 4; ++i) {
            const float4 w4 = w1[i];
            acc += w4.x * f2[4 * i + 0] + w4.y * f2[4 * i + 1]
                 + w4.z * f2[4 * i + 2] + w4.w * f2[4 * i + 3];
        }
        const float h1j = fmaxf(acc, 0.f);
        const float4* w2 = (const float4*)&s_rgb_w2[j * 64];
        #pragma unroll
        for (int q = 0; q < 16; ++q) {
            const float4 w4 = w2[q];
            h2a[4 * q + 0] += h1j * w4.x;
            h2a[4 * q + 1] += h1j * w4.y;
            h2a[4 * q + 2] += h1j * w4.z;
            h2a[4 * q + 3] += h1j * w4.w;
        }
    }
    float r0 = 0.f, r1 = 0.f, r2 = 0.f;
    #pragma unroll
    for (int k = 0; k < 64; ++k) {
        const float h2k = fmaxf(h2a[k], 0.f);
        r0 += h2k * s_rgb_w3[k * 3 + 0];
        r1 += h2k * s_rgb_w3[k * 3 + 1];
        r2 += h2k * s_rgb_w3[k * 3 + 2];
    }
    const float s0 = 1.f / (1.f + expf(-r0));
    const float s1 = 1.f / (1.f + expf(-r1));
    const float s2 = 1.f / (1.f + expf(-r2));
    float4 o; o.x = wgt; o.y = s0; o.z = s1; o.w = s2;
    ((float4*)out)[p] = o;
}

extern "C" void kernel_launch(void* const* d_in, const int* in_sizes, int n_in,
                              void* d_out, int out_size, void* d_ws, size_t ws_size,
                              hipStream_t stream) {
    const float* xyz    = (const float*)d_in[0];
    const float* delta  = (const float*)d_in[1];
    const float* table  = (const float*)d_in[2];
    const float* w_in   = (const float*)d_in[3];
    const float* w_out  = (const float*)d_in[4];
    const float* rgb_w1 = (const float*)d_in[5];
    const float* rgb_w2 = (const float*)d_in[6];
    const float* rgb_w3 = (const float*)d_in[7];
    float* outp = (float*)d_out;

    if (ws_size >= TAB16_BYTES + ENC16_BYTES) {
        __half2* tab16 = (__half2*)d_ws;
        __half2* enc16 = (__half2*)((char*)d_ws + TAB16_BYTES);

        // 1) table f32 -> fp16   (one thread per entry: 16*2^19 = 8.4M entries)
        convert_table_kernel<<<(NLVL * HASHSZ) / TPB, TPB, 0, stream>>>(
            (const float2*)table, tab16);

        // 2) level-major encode: 16 levels * 2048 chunks = 32768 blocks
        encode_kernel<<<NLVL * (NPTS / TPB), TPB, 0, stream>>>(xyz, tab16, enc16);

        // 3) MLPs + scan
        mlp_kernel<<<NPTS / TPB, TPB, 0, stream>>>(
            enc16, delta, w_in, w_out, rgb_w1, rgb_w2, rgb_w3, outp);
    } else {
        density_field_fused<<<NPTS / TPB, TPB, 0, stream>>>(
            xyz, delta, table, w_in, w_out, rgb_w1, rgb_w2, rgb_w3, outp);
    }
}